// Round 2
// baseline (235.979 us; speedup 1.0000x reference)
//
#include <hip/hip_runtime.h>
#include <hip/hip_bf16.h>
#include <math.h>

// Problem constants (match reference setup_inputs).
#define NB    4096
#define NPER  2000
#define NDIM  4
#define EPS   1e-6
#define BLOCK 256

// ---------------------------------------------------------------------------
// 4x4 symmetric eigen-penalty in double precision (cyclic Jacobi, eigenvalues
// only). Runs once per block on thread 0 — cost is negligible vs memory.
// ---------------------------------------------------------------------------
__device__ double jacobi_pen(double a00, double a01, double a02, double a03,
                             double a11, double a12, double a13,
                             double a22, double a23, double a33) {
    double A[4][4] = {
        {a00, a01, a02, a03},
        {a01, a11, a12, a13},
        {a02, a12, a22, a23},
        {a03, a13, a23, a33}
    };
    for (int sweep = 0; sweep < 15; ++sweep) {
        double off = A[0][1]*A[0][1] + A[0][2]*A[0][2] + A[0][3]*A[0][3]
                   + A[1][2]*A[1][2] + A[1][3]*A[1][3] + A[2][3]*A[2][3];
        if (off < 1e-26) break;
        for (int p = 0; p < 3; ++p) {
            for (int q = p + 1; q < 4; ++q) {
                double apq = A[p][q];
                if (fabs(apq) < 1e-300) continue;
                double app = A[p][p], aqq = A[q][q];
                double tau = (aqq - app) / (2.0 * apq);
                double t = (tau >= 0.0 ? 1.0 : -1.0) /
                           (fabs(tau) + sqrt(1.0 + tau * tau));
                double c = 1.0 / sqrt(1.0 + t * t);
                double s = t * c;
                // A = J^T * A * J : columns p,q first, then rows p,q.
                for (int k = 0; k < 4; ++k) {
                    double akp = A[k][p], akq = A[k][q];
                    A[k][p] = c * akp - s * akq;
                    A[k][q] = s * akp + c * akq;
                }
                for (int k = 0; k < 4; ++k) {
                    double apk = A[p][k], aqk = A[q][k];
                    A[p][k] = c * apk - s * aqk;
                    A[q][k] = s * apk + c * aqk;
                }
                A[p][q] = 0.0;
                A[q][p] = 0.0;
            }
        }
    }
    double e0 = A[0][0], e1 = A[1][1], e2 = A[2][2], e3 = A[3][3];
    double mean = 0.25 * (e0 + e1 + e2 + e3);
    double mn = fmin(fmin(e0, e1), fmin(e2, e3));
    double r = mean / (mn + EPS) - 1.0;
    return log(r * r + 1.0);
}

// ---------------------------------------------------------------------------
// Kernel 1: one block per event. Coalesced float4 loads (1 hit = 1 float4),
// register accumulation of 4 first moments + 10 unique second moments,
// wave shuffle reduce -> LDS -> thread-0 eigen solve.
// ---------------------------------------------------------------------------
__global__ __launch_bounds__(BLOCK)
void event_pen_kernel(const float4* __restrict__ cs, float* __restrict__ pen_out) {
    const int b = blockIdx.x;
    const float4* __restrict__ p = cs + (size_t)b * NPER;

    float s0 = 0.f, s1 = 0.f, s2 = 0.f, s3 = 0.f;
    float m00 = 0.f, m01 = 0.f, m02 = 0.f, m03 = 0.f;
    float m11 = 0.f, m12 = 0.f, m13 = 0.f;
    float m22 = 0.f, m23 = 0.f, m33 = 0.f;

    for (int i = threadIdx.x; i < NPER; i += BLOCK) {
        float4 v = p[i];
        s0 += v.x; s1 += v.y; s2 += v.z; s3 += v.w;
        m00 += v.x * v.x; m01 += v.x * v.y; m02 += v.x * v.z; m03 += v.x * v.w;
        m11 += v.y * v.y; m12 += v.y * v.z; m13 += v.y * v.w;
        m22 += v.z * v.z; m23 += v.z * v.w;
        m33 += v.w * v.w;
    }

    float vals[14] = {s0, s1, s2, s3,
                      m00, m01, m02, m03, m11, m12, m13, m22, m23, m33};

    __shared__ float red[BLOCK / 64][14];
    const int lane = threadIdx.x & 63;
    const int wave = threadIdx.x >> 6;

#pragma unroll
    for (int i = 0; i < 14; ++i) {
        float v = vals[i];
#pragma unroll
        for (int off = 32; off > 0; off >>= 1)
            v += __shfl_down(v, off, 64);
        if (lane == 0) red[wave][i] = v;
    }
    __syncthreads();

    if (threadIdx.x == 0) {
        double t[14];
#pragma unroll
        for (int i = 0; i < 14; ++i) {
            float acc = red[0][i];
            for (int w = 1; w < BLOCK / 64; ++w) acc += red[w][i];
            t[i] = (double)acc;
        }
        const double invN = 1.0 / (double)NPER;
        double mu0 = t[0] * invN, mu1 = t[1] * invN,
               mu2 = t[2] * invN, mu3 = t[3] * invN;
        double c00 = t[4]  * invN - mu0 * mu0;
        double c01 = t[5]  * invN - mu0 * mu1;
        double c02 = t[6]  * invN - mu0 * mu2;
        double c03 = t[7]  * invN - mu0 * mu3;
        double c11 = t[8]  * invN - mu1 * mu1;
        double c12 = t[9]  * invN - mu1 * mu2;
        double c13 = t[10] * invN - mu1 * mu3;
        double c22 = t[11] * invN - mu2 * mu2;
        double c23 = t[12] * invN - mu2 * mu3;
        double c33 = t[13] * invN - mu3 * mu3;

        pen_out[b] = (float)jacobi_pen(c00, c01, c02, c03,
                                       c11, c12, c13, c22, c23, c33);
    }
}

// ---------------------------------------------------------------------------
// Kernel 2: reduce NB penalties to the scalar loss. Single block, double
// accumulation, plain store (deterministic, no atomics, immune to 0xAA
// poison of d_out).
// ---------------------------------------------------------------------------
__global__ __launch_bounds__(BLOCK)
void reduce_pen_kernel(const float* __restrict__ pen, float* __restrict__ out) {
    double s = 0.0;
    for (int i = threadIdx.x; i < NB; i += BLOCK)
        s += (double)pen[i];

    __shared__ double red[BLOCK / 64];
    const int lane = threadIdx.x & 63;
    const int wave = threadIdx.x >> 6;

#pragma unroll
    for (int off = 32; off > 0; off >>= 1)
        s += __shfl_down(s, off, 64);
    if (lane == 0) red[wave] = s;
    __syncthreads();

    if (threadIdx.x == 0) {
        double tot = red[0];
        for (int w = 1; w < BLOCK / 64; ++w) tot += red[w];
        out[0] = (float)tot;
    }
}

extern "C" void kernel_launch(void* const* d_in, const int* in_sizes, int n_in,
                              void* d_out, int out_size, void* d_ws, size_t ws_size,
                              hipStream_t stream) {
    const float4* cs = (const float4*)d_in[0];   // clust_space [NB*NPER, 4] fp32
    // d_in[1] (batch_idx) is semantically a reshape key; reference ignores its
    // values (sorted equal-size groups) — never read => never fetched from HBM.
    float* pen = (float*)d_ws;                   // NB floats = 16 KB scratch
    float* out = (float*)d_out;

    event_pen_kernel<<<NB, BLOCK, 0, stream>>>(cs, pen);
    reduce_pen_kernel<<<1, BLOCK, 0, stream>>>(pen, out);
}

// Round 3
// 216.927 us; speedup vs baseline: 1.0878x; 1.0878x over previous
//
#include <hip/hip_runtime.h>
#include <hip/hip_bf16.h>
#include <math.h>

// Problem constants (match reference setup_inputs).
#define NB    4096
#define NPER  2000
#define EPS   1e-6

// ---------------------------------------------------------------------------
// Kernel 1 — pure streaming: one WAVE per event. 2000 hits = 31 full
// 64-lane float4 rounds + 16-lane tail. Register accumulation of 4 first
// moments + 10 unique second moments, wave shuffle reduce, 14 floats to ws.
// No __syncthreads, no fp64, no serial tail -> memory-bound by design.
// ---------------------------------------------------------------------------
__global__ __launch_bounds__(256)
void moments_kernel(const float4* __restrict__ cs, float* __restrict__ mom) {
    const int wave = threadIdx.x >> 6;
    const int lane = threadIdx.x & 63;
    const int b = blockIdx.x * 4 + wave;           // 1024 blocks x 4 waves = NB
    const float4* __restrict__ p = cs + (size_t)b * NPER;

    float s0 = 0.f, s1 = 0.f, s2 = 0.f, s3 = 0.f;
    float m00 = 0.f, m01 = 0.f, m02 = 0.f, m03 = 0.f;
    float m11 = 0.f, m12 = 0.f, m13 = 0.f;
    float m22 = 0.f, m23 = 0.f, m33 = 0.f;

    // 31 * 64 = 1984 hits in the uniform loop; unroll 4 for memory parallelism.
#pragma unroll 4
    for (int i = 0; i < 31; ++i) {
        float4 v = p[i * 64 + lane];
        s0 += v.x; s1 += v.y; s2 += v.z; s3 += v.w;
        m00 += v.x * v.x; m01 += v.x * v.y; m02 += v.x * v.z; m03 += v.x * v.w;
        m11 += v.y * v.y; m12 += v.y * v.z; m13 += v.y * v.w;
        m22 += v.z * v.z; m23 += v.z * v.w;
        m33 += v.w * v.w;
    }
    if (lane < 16) {                               // tail: hits 1984..1999
        float4 v = p[1984 + lane];
        s0 += v.x; s1 += v.y; s2 += v.z; s3 += v.w;
        m00 += v.x * v.x; m01 += v.x * v.y; m02 += v.x * v.z; m03 += v.x * v.w;
        m11 += v.y * v.y; m12 += v.y * v.z; m13 += v.y * v.w;
        m22 += v.z * v.z; m23 += v.z * v.w;
        m33 += v.w * v.w;
    }

    float vals[14] = {s0, s1, s2, s3,
                      m00, m01, m02, m03, m11, m12, m13, m22, m23, m33};
#pragma unroll
    for (int j = 0; j < 14; ++j) {
        float v = vals[j];
#pragma unroll
        for (int off = 32; off > 0; off >>= 1)
            v += __shfl_down(v, off, 64);
        vals[j] = v;
    }

    if (lane == 0) {
        float* o = mom + (size_t)b * 16;           // 64B stride per event
#pragma unroll
        for (int j = 0; j < 14; ++j) o[j] = vals[j];
    }
}

// ---------------------------------------------------------------------------
// Kernel 2 — one THREAD per event: fp64 cov + cyclic Jacobi (all 64 lanes
// busy, wave-uniform sweeps with __all early exit), penalty, block reduce,
// one atomicAdd per block into d_out (pre-zeroed via hipMemsetAsync).
// ---------------------------------------------------------------------------
__global__ __launch_bounds__(256)
void pen_kernel(const float* __restrict__ mom, float* __restrict__ out) {
    const int b = blockIdx.x * 256 + threadIdx.x;  // 16 blocks x 256 = NB
    const float* m = mom + (size_t)b * 16;

    double t[14];
#pragma unroll
    for (int j = 0; j < 14; ++j) t[j] = (double)m[j];

    const double invN = 1.0 / (double)NPER;
    double mu0 = t[0] * invN, mu1 = t[1] * invN,
           mu2 = t[2] * invN, mu3 = t[3] * invN;

    double A[4][4];
    A[0][0] = t[4]  * invN - mu0 * mu0;
    A[0][1] = A[1][0] = t[5]  * invN - mu0 * mu1;
    A[0][2] = A[2][0] = t[6]  * invN - mu0 * mu2;
    A[0][3] = A[3][0] = t[7]  * invN - mu0 * mu3;
    A[1][1] = t[8]  * invN - mu1 * mu1;
    A[1][2] = A[2][1] = t[9]  * invN - mu1 * mu2;
    A[1][3] = A[3][1] = t[10] * invN - mu1 * mu3;
    A[2][2] = t[11] * invN - mu2 * mu2;
    A[2][3] = A[3][2] = t[12] * invN - mu2 * mu3;
    A[3][3] = t[13] * invN - mu3 * mu3;

    for (int sweep = 0; sweep < 10; ++sweep) {
        double off = A[0][1]*A[0][1] + A[0][2]*A[0][2] + A[0][3]*A[0][3]
                   + A[1][2]*A[1][2] + A[1][3]*A[1][3] + A[2][3]*A[2][3];
        if (__all(off < 1e-26)) break;             // wave-uniform exit
#pragma unroll
        for (int p = 0; p < 3; ++p) {
#pragma unroll
            for (int q = p + 1; q < 4; ++q) {
                double apq = A[p][q];
                if (fabs(apq) > 1e-300) {
                    double tau = (A[q][q] - A[p][p]) / (2.0 * apq);
                    double tt = (tau >= 0.0 ? 1.0 : -1.0) /
                                (fabs(tau) + sqrt(1.0 + tau * tau));
                    double c = 1.0 / sqrt(1.0 + tt * tt);
                    double s = tt * c;
#pragma unroll
                    for (int k = 0; k < 4; ++k) {
                        double akp = A[k][p], akq = A[k][q];
                        A[k][p] = c * akp - s * akq;
                        A[k][q] = s * akp + c * akq;
                    }
#pragma unroll
                    for (int k = 0; k < 4; ++k) {
                        double apk = A[p][k], aqk = A[q][k];
                        A[p][k] = c * apk - s * aqk;
                        A[q][k] = s * apk + c * aqk;
                    }
                    A[p][q] = 0.0;
                    A[q][p] = 0.0;
                }
            }
        }
    }

    double e0 = A[0][0], e1 = A[1][1], e2 = A[2][2], e3 = A[3][3];
    double mean = 0.25 * (e0 + e1 + e2 + e3);
    double mn = fmin(fmin(e0, e1), fmin(e2, e3));
    double r = mean / (mn + EPS) - 1.0;
    float pen = (float)log(r * r + 1.0);

    // Block reduction -> one atomic per block.
    const int lane = threadIdx.x & 63;
    const int wv = threadIdx.x >> 6;
    __shared__ float red[4];
#pragma unroll
    for (int off = 32; off > 0; off >>= 1)
        pen += __shfl_down(pen, off, 64);
    if (lane == 0) red[wv] = pen;
    __syncthreads();
    if (threadIdx.x == 0) {
        float s = red[0] + red[1] + red[2] + red[3];
        atomicAdd(out, s);
    }
}

extern "C" void kernel_launch(void* const* d_in, const int* in_sizes, int n_in,
                              void* d_out, int out_size, void* d_ws, size_t ws_size,
                              hipStream_t stream) {
    const float4* cs = (const float4*)d_in[0];   // clust_space [NB*NPER, 4] fp32
    // d_in[1] (batch_idx) is a pure reshape key for sorted equal groups —
    // reference semantics never depend on its values; never fetched.
    float* mom = (float*)d_ws;                   // NB * 16 floats = 256 KB
    float* out = (float*)d_out;

    hipMemsetAsync(out, 0, sizeof(float), stream);   // d_out is 0xAA-poisoned
    moments_kernel<<<NB / 4, 256, 0, stream>>>(cs, mom);
    pen_kernel<<<NB / 256, 256, 0, stream>>>(mom, out);
}

// Round 5
// 211.915 us; speedup vs baseline: 1.1136x; 1.0237x over previous
//
#include <hip/hip_runtime.h>
#include <hip/hip_bf16.h>
#include <math.h>

// Problem constants (match reference setup_inputs).
#define NB    4096
#define NPER  2000
#define HALF  1000        // hits per half-event (one wave each)
#define EPS   1e-6

// ---------------------------------------------------------------------------
// Kernel 1 — pure streaming: one WAVE per HALF-event (8192 waves total =
// 32 waves/CU, max occupancy). 1000 hits = 15 full 64-lane float4 rounds
// (fully unrolled -> many loads in flight) + 40-lane tail. Register
// accumulation of 14 partial moments, wave shuffle reduce, 14 floats to ws.
// No __syncthreads, no fp64 -> memory-bound by design.
// ---------------------------------------------------------------------------
__global__ __launch_bounds__(256)
void moments_kernel(const float4* __restrict__ cs, float* __restrict__ mom) {
    const int wave = threadIdx.x >> 6;
    const int lane = threadIdx.x & 63;
    const int h = blockIdx.x * 4 + wave;           // 2048 blocks x 4 waves = 2*NB
    const float4* __restrict__ p = cs + (size_t)h * HALF;

    float s0 = 0.f, s1 = 0.f, s2 = 0.f, s3 = 0.f;
    float m00 = 0.f, m01 = 0.f, m02 = 0.f, m03 = 0.f;
    float m11 = 0.f, m12 = 0.f, m13 = 0.f;
    float m22 = 0.f, m23 = 0.f, m33 = 0.f;

    // 15 * 64 = 960 hits, fully unrolled for maximum loads-in-flight.
#pragma unroll
    for (int i = 0; i < 15; ++i) {
        float4 v = p[i * 64 + lane];
        s0 += v.x; s1 += v.y; s2 += v.z; s3 += v.w;
        m00 += v.x * v.x; m01 += v.x * v.y; m02 += v.x * v.z; m03 += v.x * v.w;
        m11 += v.y * v.y; m12 += v.y * v.z; m13 += v.y * v.w;
        m22 += v.z * v.z; m23 += v.z * v.w;
        m33 += v.w * v.w;
    }
    if (lane < 40) {                               // tail: hits 960..999
        float4 v = p[960 + lane];
        s0 += v.x; s1 += v.y; s2 += v.z; s3 += v.w;
        m00 += v.x * v.x; m01 += v.x * v.y; m02 += v.x * v.z; m03 += v.x * v.w;
        m11 += v.y * v.y; m12 += v.y * v.z; m13 += v.y * v.w;
        m22 += v.z * v.z; m23 += v.z * v.w;
        m33 += v.w * v.w;
    }

    float vals[14] = {s0, s1, s2, s3,
                      m00, m01, m02, m03, m11, m12, m13, m22, m23, m33};
#pragma unroll
    for (int j = 0; j < 14; ++j) {
        float v = vals[j];
#pragma unroll
        for (int off = 32; off > 0; off >>= 1)
            v += __shfl_down(v, off, 64);
        vals[j] = v;
    }

    if (lane == 0) {
        float* o = mom + (size_t)h * 16;           // 64B stride per half-event
#pragma unroll
        for (int j = 0; j < 14; ++j) o[j] = vals[j];
    }
}

// ---------------------------------------------------------------------------
// Kernel 2 — one THREAD per event (64 blocks x 64 threads = 64 CUs, 1 wave
// each, no LDS/barrier): combine the two half-moments, fp64 cov + cyclic
// Jacobi (wave-uniform sweeps with __all early exit), penalty, wave reduce,
// one atomicAdd per wave into d_out (pre-zeroed via hipMemsetAsync).
// ---------------------------------------------------------------------------
__global__ __launch_bounds__(64)
void pen_kernel(const float* __restrict__ mom, float* __restrict__ out) {
    const int b = blockIdx.x * 64 + threadIdx.x;   // 64 x 64 = NB events
    const float* mA = mom + (size_t)(2 * b)     * 16;
    const float* mB = mom + (size_t)(2 * b + 1) * 16;

    double t[14];
#pragma unroll
    for (int j = 0; j < 14; ++j) t[j] = (double)mA[j] + (double)mB[j];

    const double invN = 1.0 / (double)NPER;
    double mu0 = t[0] * invN, mu1 = t[1] * invN,
           mu2 = t[2] * invN, mu3 = t[3] * invN;

    double A[4][4];
    A[0][0] = t[4]  * invN - mu0 * mu0;
    A[0][1] = A[1][0] = t[5]  * invN - mu0 * mu1;
    A[0][2] = A[2][0] = t[6]  * invN - mu0 * mu2;
    A[0][3] = A[3][0] = t[7]  * invN - mu0 * mu3;
    A[1][1] = t[8]  * invN - mu1 * mu1;
    A[1][2] = A[2][1] = t[9]  * invN - mu1 * mu2;
    A[1][3] = A[3][1] = t[10] * invN - mu1 * mu3;
    A[2][2] = t[11] * invN - mu2 * mu2;
    A[2][3] = A[3][2] = t[12] * invN - mu2 * mu3;
    A[3][3] = t[13] * invN - mu3 * mu3;

    for (int sweep = 0; sweep < 8; ++sweep) {
        double off = A[0][1]*A[0][1] + A[0][2]*A[0][2] + A[0][3]*A[0][3]
                   + A[1][2]*A[1][2] + A[1][3]*A[1][3] + A[2][3]*A[2][3];
        if (__all(off < 1e-24)) break;             // wave-uniform exit
#pragma unroll
        for (int p = 0; p < 3; ++p) {
#pragma unroll
            for (int q = p + 1; q < 4; ++q) {
                double apq = A[p][q];
                if (fabs(apq) > 1e-300) {
                    double tau = (A[q][q] - A[p][p]) / (2.0 * apq);
                    double tt = (tau >= 0.0 ? 1.0 : -1.0) /
                                (fabs(tau) + sqrt(1.0 + tau * tau));
                    double c = 1.0 / sqrt(1.0 + tt * tt);
                    double s = tt * c;
#pragma unroll
                    for (int k = 0; k < 4; ++k) {
                        double akp = A[k][p], akq = A[k][q];
                        A[k][p] = c * akp - s * akq;
                        A[k][q] = s * akp + c * akq;
                    }
#pragma unroll
                    for (int k = 0; k < 4; ++k) {
                        double apk = A[p][k], aqk = A[q][k];
                        A[p][k] = c * apk - s * aqk;
                        A[q][k] = s * apk + c * aqk;
                    }
                    A[p][q] = 0.0;
                    A[q][p] = 0.0;
                }
            }
        }
    }

    double e0 = A[0][0], e1 = A[1][1], e2 = A[2][2], e3 = A[3][3];
    double mean = 0.25 * (e0 + e1 + e2 + e3);
    double mn = fmin(fmin(e0, e1), fmin(e2, e3));
    double r = mean / (mn + EPS) - 1.0;
    float pen = (float)log(r * r + 1.0);

    // Wave reduction -> one atomic per wave (64 atomics total).
#pragma unroll
    for (int off = 32; off > 0; off >>= 1)
        pen += __shfl_down(pen, off, 64);
    if (threadIdx.x == 0)
        atomicAdd(out, pen);
}

extern "C" void kernel_launch(void* const* d_in, const int* in_sizes, int n_in,
                              void* d_out, int out_size, void* d_ws, size_t ws_size,
                              hipStream_t stream) {
    const float4* cs = (const float4*)d_in[0];   // clust_space [NB*NPER, 4] fp32
    // d_in[1] (batch_idx) is a pure reshape key for sorted equal groups —
    // reference semantics never depend on its values; never fetched.
    float* mom = (float*)d_ws;                   // 2*NB * 16 floats = 512 KB
    float* out = (float*)d_out;

    hipMemsetAsync(out, 0, sizeof(float), stream);   // d_out is 0xAA-poisoned
    moments_kernel<<<2 * NB / 4, 256, 0, stream>>>(cs, mom);
    pen_kernel<<<NB / 64, 64, 0, stream>>>(mom, out);
}

// Round 6
// 211.252 us; speedup vs baseline: 1.1170x; 1.0031x over previous
//
#include <hip/hip_runtime.h>
#include <hip/hip_bf16.h>
#include <math.h>

// Problem constants (match reference setup_inputs).
#define NB     4096
#define NPER   2000
#define HALF   1000          // hits per half-event
#define HALVES (2 * NB)      // 8192 half-events
#define WGS    512           // workgroups in moments pass
#define WAVES  (WGS * 4)     // 2048 waves; each handles HALVES/WAVES = 4 chunks
#define EPS    1e-6

#define ACC(v)                                                             \
    do {                                                                   \
        s0 += (v).x; s1 += (v).y; s2 += (v).z; s3 += (v).w;                \
        m00 += (v).x * (v).x; m01 += (v).x * (v).y;                        \
        m02 += (v).x * (v).z; m03 += (v).x * (v).w;                        \
        m11 += (v).y * (v).y; m12 += (v).y * (v).z; m13 += (v).y * (v).w;  \
        m22 += (v).z * (v).z; m23 += (v).z * (v).w;                        \
        m33 += (v).w * (v).w;                                              \
    } while (0)

// ---------------------------------------------------------------------------
// Kernel 1 — persistent streaming: 512 WGs x 256 threads = 2048 waves; each
// wave loops over 4 half-events (1000 hits each). Loads batched 8-deep into
// independent registers (guaranteed MLP), 14-moment register accumulation,
// wave shuffle reduce, packed float4 stores. No barriers, no fp64, long-lived
// waves -> no workgroup churn.
// ---------------------------------------------------------------------------
__global__ __launch_bounds__(256)
void moments_kernel(const float4* __restrict__ cs, float* __restrict__ mom) {
    const int wave = threadIdx.x >> 6;
    const int lane = threadIdx.x & 63;
    const int w0 = blockIdx.x * 4 + wave;

    for (int e = 0; e < HALVES / WAVES; ++e) {
        const int h = w0 + e * WAVES;
        const float4* __restrict__ p = cs + (size_t)h * HALF;

        float s0 = 0.f, s1 = 0.f, s2 = 0.f, s3 = 0.f;
        float m00 = 0.f, m01 = 0.f, m02 = 0.f, m03 = 0.f;
        float m11 = 0.f, m12 = 0.f, m13 = 0.f;
        float m22 = 0.f, m23 = 0.f, m33 = 0.f;

        // Batch 1: rounds 0..7 (8 loads in flight, then their FMAs).
        float4 v[8];
#pragma unroll
        for (int r = 0; r < 8; ++r) v[r] = p[r * 64 + lane];
#pragma unroll
        for (int r = 0; r < 8; ++r) ACC(v[r]);

        // Batch 2: rounds 8..14 (7 loads) + masked tail (hits 960..999).
#pragma unroll
        for (int r = 0; r < 7; ++r) v[r] = p[512 + r * 64 + lane];
        float4 vt = p[960 + (lane < 40 ? lane : 0)];
        if (lane >= 40) { vt.x = 0.f; vt.y = 0.f; vt.z = 0.f; vt.w = 0.f; }
#pragma unroll
        for (int r = 0; r < 7; ++r) ACC(v[r]);
        ACC(vt);

        float vals[14] = {s0, s1, s2, s3,
                          m00, m01, m02, m03, m11, m12, m13, m22, m23, m33};
#pragma unroll
        for (int j = 0; j < 14; ++j) {
            float x = vals[j];
#pragma unroll
            for (int off = 32; off > 0; off >>= 1)
                x += __shfl_down(x, off, 64);
            vals[j] = x;
        }

        if (lane == 0) {
            float4* o = (float4*)(mom + (size_t)h * 16);   // 64B/half-event
            o[0] = make_float4(vals[0], vals[1], vals[2],  vals[3]);
            o[1] = make_float4(vals[4], vals[5], vals[6],  vals[7]);
            o[2] = make_float4(vals[8], vals[9], vals[10], vals[11]);
            o[3] = make_float4(vals[12], vals[13], 0.f, 0.f);
        }
    }
}

// ---------------------------------------------------------------------------
// Kernel 2 — one THREAD per event (64 blocks x 64 threads): combine the two
// half-moments, fp64 cov + cyclic Jacobi (wave-uniform sweeps with __all
// early exit), penalty, wave reduce, one atomicAdd per wave into d_out
// (pre-zeroed via hipMemsetAsync).
// ---------------------------------------------------------------------------
__global__ __launch_bounds__(64)
void pen_kernel(const float* __restrict__ mom, float* __restrict__ out) {
    const int b = blockIdx.x * 64 + threadIdx.x;   // 64 x 64 = NB events
    const float* mA = mom + (size_t)(2 * b)     * 16;
    const float* mB = mom + (size_t)(2 * b + 1) * 16;

    double t[14];
#pragma unroll
    for (int j = 0; j < 14; ++j) t[j] = (double)mA[j] + (double)mB[j];

    const double invN = 1.0 / (double)NPER;
    double mu0 = t[0] * invN, mu1 = t[1] * invN,
           mu2 = t[2] * invN, mu3 = t[3] * invN;

    double A[4][4];
    A[0][0] = t[4]  * invN - mu0 * mu0;
    A[0][1] = A[1][0] = t[5]  * invN - mu0 * mu1;
    A[0][2] = A[2][0] = t[6]  * invN - mu0 * mu2;
    A[0][3] = A[3][0] = t[7]  * invN - mu0 * mu3;
    A[1][1] = t[8]  * invN - mu1 * mu1;
    A[1][2] = A[2][1] = t[9]  * invN - mu1 * mu2;
    A[1][3] = A[3][1] = t[10] * invN - mu1 * mu3;
    A[2][2] = t[11] * invN - mu2 * mu2;
    A[2][3] = A[3][2] = t[12] * invN - mu2 * mu3;
    A[3][3] = t[13] * invN - mu3 * mu3;

    for (int sweep = 0; sweep < 8; ++sweep) {
        double off = A[0][1]*A[0][1] + A[0][2]*A[0][2] + A[0][3]*A[0][3]
                   + A[1][2]*A[1][2] + A[1][3]*A[1][3] + A[2][3]*A[2][3];
        if (__all(off < 1e-24)) break;             // wave-uniform exit
#pragma unroll
        for (int p = 0; p < 3; ++p) {
#pragma unroll
            for (int q = p + 1; q < 4; ++q) {
                double apq = A[p][q];
                if (fabs(apq) > 1e-300) {
                    double tau = (A[q][q] - A[p][p]) / (2.0 * apq);
                    double tt = (tau >= 0.0 ? 1.0 : -1.0) /
                                (fabs(tau) + sqrt(1.0 + tau * tau));
                    double c = 1.0 / sqrt(1.0 + tt * tt);
                    double s = tt * c;
#pragma unroll
                    for (int k = 0; k < 4; ++k) {
                        double akp = A[k][p], akq = A[k][q];
                        A[k][p] = c * akp - s * akq;
                        A[k][q] = s * akp + c * akq;
                    }
#pragma unroll
                    for (int k = 0; k < 4; ++k) {
                        double apk = A[p][k], aqk = A[q][k];
                        A[p][k] = c * apk - s * aqk;
                        A[q][k] = s * apk + c * aqk;
                    }
                    A[p][q] = 0.0;
                    A[q][p] = 0.0;
                }
            }
        }
    }

    double e0 = A[0][0], e1 = A[1][1], e2 = A[2][2], e3 = A[3][3];
    double mean = 0.25 * (e0 + e1 + e2 + e3);
    double mn = fmin(fmin(e0, e1), fmin(e2, e3));
    double r = mean / (mn + EPS) - 1.0;
    float pen = (float)log(r * r + 1.0);

    // Wave reduction -> one atomic per wave (64 atomics total).
#pragma unroll
    for (int off = 32; off > 0; off >>= 1)
        pen += __shfl_down(pen, off, 64);
    if (threadIdx.x == 0)
        atomicAdd(out, pen);
}

extern "C" void kernel_launch(void* const* d_in, const int* in_sizes, int n_in,
                              void* d_out, int out_size, void* d_ws, size_t ws_size,
                              hipStream_t stream) {
    const float4* cs = (const float4*)d_in[0];   // clust_space [NB*NPER, 4] fp32
    // d_in[1] (batch_idx) is a pure reshape key for sorted equal groups —
    // reference semantics never depend on its values; never fetched.
    float* mom = (float*)d_ws;                   // 2*NB * 16 floats = 512 KB
    float* out = (float*)d_out;

    hipMemsetAsync(out, 0, sizeof(float), stream);   // d_out is 0xAA-poisoned
    moments_kernel<<<WGS, 256, 0, stream>>>(cs, mom);
    pen_kernel<<<NB / 64, 64, 0, stream>>>(mom, out);
}